// Round 5
// baseline (100.673 us; speedup 1.0000x reference)
//
#include <hip/hip_runtime.h>

// Problem constants
#define B_    16
#define A_    3
#define C_    80
#define H_    52
#define W_    52
#define T_    50
#define PLANE (H_*W_)                 // 2704
#define BSTRIDE (A_*(5+C_)*PLANE)     // 689520 floats per batch image
#define NLOCF 129792.0f               // B*H*W*A
#define NQ    (PLANE/4)               // 676 float4 groups per plane
#define NCH   (A_*81)                 // 243 channels per image we stream (f=4..84)
#define TOTU  (B_*NCH*NQ)             // 2,627,568 float4 groups
#define NBA   1024                    // blocks
#define NTHR  256
#define GRIDT (NBA*NTHR)
#define NCOMP 11
#define CLIPV 16.1180957f             // -log(1e-7)
#define BCE00 1.1920929e-07f          // -log(1 - 1e-7) in f32 (= BCE(clip(0), 0))
// acc: 0:x 1:y 2:w 3:h 4:conf_obj 5:conf_noobj(neg) 6:cls(neg) 7:npos 8:nmark
//      9:S_conf 10:S_cls

__device__ __forceinline__ float sigf(float x){ return 1.0f/(1.0f+__expf(-x)); }
__device__ __forceinline__ float clipp(float p){ return fminf(fmaxf(p, 1e-7f), 1.0f-1e-7f); }
// -log(1 - clip(sigmoid(v))) == min(softplus(v), -log(1e-7)); low-clip branch
// differs by <1e-7 per element and only for v < -16.1 (absent in N(0,1) data).
__device__ __forceinline__ float softp(float v){ return fminf(__logf(1.0f+__expf(v)), CLIPV); }

// Single fused kernel: every block redundantly builds the (tiny) target/dedup
// state in LDS (~1 us; tgt is 16 KB, L2-broadcast), then processes its slice of
// correction items + the coalesced streaming reduce. 11 partials per block.
// LDS: 8 KB winner hash + 16 KB mark-set/winner-record overlay + 9.6 KB mark
// list ~= 34 KB -> 4 blocks/CU at 256 thr (occupancy preserved vs round 4).
__global__ __launch_bounds__(NTHR) void fused(
        const float* __restrict__ pred, const float* __restrict__ tgt,
        float* __restrict__ partial){
    __shared__ int hkey[1024], hval[1024];  // winner hash: loc -> max flat idx+1
    __shared__ int mlist[2400];             // compact conf-offset list (marks)
    __shared__ int wm[4096];                // phase A: mark set; phase B+: winner
                                            // records {off,tx,ty,tw,th} x <=800
    __shared__ int mnum, wnum;
    const float AW[3]={14.5f,19.5f,46.625f};   // ANCHORS / 8
    const float AH[3]={11.25f,24.75f,40.75f};
    const int tid = threadIdx.x;

    for (int s=tid; s<1024; s+=NTHR){ hkey[s]=-1; hval[s]=0; }
    for (int s=tid; s<4096; s+=NTHR) wm[s]=-1;
    if (tid==0){ mnum=0; wnum=0; }
    __syncthreads();

    // ---- Phase A: hash inserts (winner last-write-wins, unique marks) ----
    for (int i=tid; i<B_*T_; i+=NTHR){
        const float* r = tgt + i*5;
        if (r[0]+r[1]+r[2]+r[3]+r[4] > 0.0f){
            int b = i / T_;
            float gx=r[1]*(float)W_, gy=r[2]*(float)H_;
            float gw=r[3]*(float)W_, gh=r[4]*(float)H_;
            int gi=(int)gx, gj=(int)gy;
            float best_iou=-1.0f; int best=0, mask=0;
            #pragma unroll
            for (int a=0;a<3;a++){
                float inter = fminf(gw, AW[a]) * fminf(gh, AH[a]);
                float iou = inter / (gw*gh + AW[a]*AH[a] - inter + 1e-16f);
                if (iou > best_iou){ best_iou=iou; best=a; }
                if (iou > 0.5f) mask |= (1<<a);
            }
            int cell = (b*H_ + gi)*W_ + gj;  // gi (from x) indexes H — ref quirk
            int loc  = cell*A_ + best;
            int s = (int)(((unsigned)loc * 2654435761u) >> 22) & 1023;
            for (;;){
                int old = atomicCAS(&hkey[s], -1, loc);
                if (old == -1 || old == loc){ atomicMax(&hval[s], i+1); break; }
                s = (s+1) & 1023;
            }
            #pragma unroll
            for (int a=0;a<3;a++) if ((mask>>a)&1){
                int key = cell*A_ + a;
                int m = (int)(((unsigned)key * 2654435761u) >> 20) & 4095;
                for (;;){
                    int old = atomicCAS(&wm[m], -1, key);
                    if (old == -1){
                        int ix = atomicAdd(&mnum, 1);
                        mlist[ix] = b*BSTRIDE + (a*85+4)*PLANE + (cell - b*PLANE);
                        break;
                    }
                    if (old == key) break;    // duplicate
                    m = (m+1) & 4095;
                }
            }
        }
    }
    __syncthreads();

    // ---- Phase B: emit winner records (overlay wm; mark set dead now) ----
    for (int i=tid; i<B_*T_; i+=NTHR){
        const float* r = tgt + i*5;
        if (r[0]+r[1]+r[2]+r[3]+r[4] > 0.0f){
            int b = i / T_;
            float gx=r[1]*(float)W_, gy=r[2]*(float)H_;
            float gw=r[3]*(float)W_, gh=r[4]*(float)H_;
            int gi=(int)gx, gj=(int)gy;
            float best_iou=-1.0f; int best=0;
            #pragma unroll
            for (int a=0;a<3;a++){
                float inter = fminf(gw, AW[a]) * fminf(gh, AH[a]);
                float iou = inter / (gw*gh + AW[a]*AH[a] - inter + 1e-16f);
                if (iou > best_iou){ best_iou=iou; best=a; }
            }
            int cell = (b*H_ + gi)*W_ + gj;
            int loc  = cell*A_ + best;
            int s = (int)(((unsigned)loc * 2654435761u) >> 22) & 1023;
            while (hkey[s] != loc) s = (s+1) & 1023;
            if (hval[s] == i+1){             // this target wins loc
                int ix = atomicAdd(&wnum, 1);
                wm[5*ix+0] = b*BSTRIDE + best*85*PLANE + gi*W_ + gj;
                wm[5*ix+1] = __float_as_int(gx-(float)gi);
                wm[5*ix+2] = __float_as_int(gy-(float)gj);
                wm[5*ix+3] = __float_as_int(logf(gw/AW[best] + 1e-16f));
                wm[5*ix+4] = __float_as_int(logf(gh/AH[best] + 1e-16f));
            }
        }
    }
    __syncthreads();

    float acc[NCOMP];
    #pragma unroll
    for (int k=0;k<NCOMP;k++) acc[k]=0.0f;

    const unsigned gid = blockIdx.x*NTHR + tid;

    // ---- Phase C: correction items (records from LDS, pred loads scattered) --
    const int ncw = wnum, ncm = mnum;
    const int nitems = ncw*81 + ncm;
    for (int j = (int)gid; j < nitems; j += GRIDT){
        if (j < ncw*81){
            int w = j / 81, k = j - w*81;
            const float* base = pred + wm[5*w];
            if (k == 0){
                float px=base[0], py=base[PLANE], pw=base[2*PLANE],
                      ph=base[3*PLANE], pc=base[4*PLANE];
                float tx=__int_as_float(wm[5*w+1]), ty=__int_as_float(wm[5*w+2]);
                float tw=__int_as_float(wm[5*w+3]), th=__int_as_float(wm[5*w+4]);
                float p = clipp(sigf(px));
                acc[0] += -(tx*__logf(p) + (1.0f-tx)*__logf(1.0f-p)) - BCE00;
                p = clipp(sigf(py));
                acc[1] += -(ty*__logf(p) + (1.0f-ty)*__logf(1.0f-p)) - BCE00;
                float dw=pw-tw; acc[2]+=dw*dw;
                float dh=ph-th; acc[3]+=dh*dh;
                p = clipp(sigf(pc));
                acc[4] += -__logf(p) - BCE00;
                acc[7] += 1.0f;
            } else {
                // class channel 4+k at an obj loc is excluded (m0==0): remove
                acc[6] -= softp(base[(4+k)*PLANE]);
            }
        } else {
            acc[5] -= softp(pred[mlist[j - ncw*81]]);
            acc[8] += 1.0f;
        }
    }

    // ---- Phase D: streaming reduce (obj=0/noobj=1 baseline) ----
    for (unsigned u = gid; u < TOTU; u += GRIDT){
        unsigned q  = u % NQ;
        unsigned t  = u / NQ;            // b*NCH + p
        unsigned p  = t % NCH;
        unsigned b  = t / NCH;
        unsigned a  = p / 81u;
        unsigned fr = p - a*81u;         // 0 => conf, else class
        unsigned c  = a*85u + 4u + fr;   // channel in (B,255,H,W)
        const float4 v4 = *(const float4*)(pred + b*BSTRIDE + c*PLANE + q*4u);
        float s = softp(v4.x) + softp(v4.y) + softp(v4.z) + softp(v4.w);
        if (fr == 0u) acc[9] += s; else acc[10] += s;
    }

    // ---- Phase E: block reduce, write partials ----
    #pragma unroll
    for (int k=0;k<NCOMP;k++)
        for (int off=32; off; off>>=1)
            acc[k] += __shfl_down(acc[k], off, 64);
    __shared__ float l[4][NCOMP];
    int lane = tid & 63, wv = tid >> 6;
    if (lane == 0){
        #pragma unroll
        for (int k=0;k<NCOMP;k++) l[wv][k] = acc[k];
    }
    __syncthreads();
    if (tid < NCOMP)
        partial[tid*NBA + blockIdx.x] = l[0][tid]+l[1][tid]+l[2][tid]+l[3][tid];
}

__global__ __launch_bounds__(1024) void finalize(const float* __restrict__ partial,
                                                 float* __restrict__ out){
    int i = threadIdx.x;
    float acc[NCOMP];
    #pragma unroll
    for (int k=0;k<NCOMP;k++) acc[k] = partial[k*NBA + i];
    #pragma unroll
    for (int k=0;k<NCOMP;k++)
        for (int off=32; off; off>>=1)
            acc[k] += __shfl_down(acc[k], off, 64);
    __shared__ float red[16][NCOMP];
    int lane = i & 63, wv = i >> 6;
    if (lane == 0){
        #pragma unroll
        for (int k=0;k<NCOMP;k++) red[wv][k]=acc[k];
    }
    __syncthreads();
    if (i == 0){
        float c[NCOMP];
        #pragma unroll
        for (int k=0;k<NCOMP;k++){
            float s=0.0f;
            for (int w=0;w<16;w++) s += red[w][k];
            c[k]=s;
        }
        const float Nf = NLOCF;
        float lx    = BCE00 + c[0]/Nf;
        float ly    = BCE00 + c[1]/Nf;
        float lw    = c[2]/Nf;
        float lh    = c[3]/Nf;
        float lconf = (BCE00 + c[4]/Nf) + 0.5f*(c[9] + c[5] + c[8]*BCE00)/Nf;
        float lcls  = (c[10] + c[6]) / ((Nf - c[7])*(float)C_);
        float loss  = 2.5f*(lx+ly+lw+lh) + lconf + lcls;
        out[0]=loss; out[1]=lx; out[2]=ly; out[3]=lw; out[4]=lh; out[5]=lconf; out[6]=lcls;
    }
}

extern "C" void kernel_launch(void* const* d_in, const int* in_sizes, int n_in,
                              void* d_out, int out_size, void* d_ws, size_t ws_size,
                              hipStream_t stream) {
    const float* pred = (const float*)d_in[0];   // (16,255,52,52) f32
    const float* tgt  = (const float*)d_in[1];   // (16,50,5) f32
    float* partial = (float*)d_ws;               // NCOMP*NBA floats, overwritten

    fused<<<NBA, NTHR, 0, stream>>>(pred, tgt, partial);
    finalize<<<1, 1024, 0, stream>>>(partial, (float*)d_out);
}